// Round 6
// baseline (87.349 us; speedup 1.0000x reference)
//
#include <hip/hip_runtime.h>

// B=256, IN_F=512, K_INT=75 (pad 80), OUT_F=64
// ws: Tb[o][k_pad80][f] bf16 @ 0         (64*80*512*2 = 5,242,880 B)
//     xb[b][f]          bf16 @ 5,242,880 (256*512*2   =   262,144 B)

typedef __attribute__((ext_vector_type(8))) short bf16x8;
typedef __attribute__((ext_vector_type(4))) float f32x4;
typedef unsigned short u16;
typedef unsigned int u32;

__device__ inline u16 f2bf(float f) {            // RNE float->bf16 bits
  u32 u = __float_as_uint(f);
  return (u16)((u + 0x7FFFu + ((u >> 16) & 1u)) >> 16);
}

// ---------- x[256][512] fp32 -> xb[b][f] bf16 ----------
__global__ __launch_bounds__(256) void cvt_x(const float* __restrict__ x,
                                             u16* __restrict__ xb) {
  const int i = blockIdx.x * 256 + threadIdx.x;  // 16384 threads x 8 elems
  const float4* x4 = reinterpret_cast<const float4*>(x);
  const float4 v0 = x4[i * 2], v1 = x4[i * 2 + 1];
  uint4 o;
  o.x = (u32)f2bf(v0.x) | ((u32)f2bf(v0.y) << 16);
  o.y = (u32)f2bf(v0.z) | ((u32)f2bf(v0.w) << 16);
  o.z = (u32)f2bf(v1.x) | ((u32)f2bf(v1.y) << 16);
  o.w = (u32)f2bf(v1.z) | ((u32)f2bf(v1.w) << 16);
  *reinterpret_cast<uint4*>(xb + i * 8) = o;
}

// ---------- T[f][k][o] fp32 -> Tb[o][k_pad80][f] bf16 (pad rows zeroed) ----------
__global__ __launch_bounds__(256) void cvt_T(const float* __restrict__ T,
                                             u16* __restrict__ Tb) {
  const int f0 = blockIdx.x << 6;    // f-tile 0..7
  const int k = blockIdx.y;          // 0..79
  const int tid = threadIdx.x;
  const int w = tid >> 2;            // o row 0..63
  const int c = tid & 3;
  u16* dst = Tb + (w * 80 + k) * 512 + f0 + (c << 4);

  if (k >= 75) {                     // zero-fill pad rows (keeps MFMA NaN-free)
    const uint4 z = make_uint4(0, 0, 0, 0);
    reinterpret_cast<uint4*>(dst)[0] = z;
    reinterpret_cast<uint4*>(dst)[1] = z;
    return;
  }

  __shared__ float tile[64][65];     // [f_local][o], pad 65
  const float4* T4 = reinterpret_cast<const float4*>(T);
#pragma unroll
  for (int h = 0; h < 4; ++h) {
    const int idx = (h << 8) + tid;  // 0..1023
    const int r = idx >> 4;          // f row 0..63
    const int q = idx & 15;          // o-quad
    const float4 v = T4[(f0 + r) * 1200 + k * 16 + q];   // 256B-contig per 16 lanes
    tile[r][(q << 2) + 0] = v.x;
    tile[r][(q << 2) + 1] = v.y;
    tile[r][(q << 2) + 2] = v.z;
    tile[r][(q << 2) + 3] = v.w;
  }
  __syncthreads();

  u16 us[16];
#pragma unroll
  for (int j = 0; j < 16; ++j) us[j] = f2bf(tile[(c << 4) + j][w]);
  uint4 p0, p1;
  p0.x = (u32)us[0] | ((u32)us[1] << 16);
  p0.y = (u32)us[2] | ((u32)us[3] << 16);
  p0.z = (u32)us[4] | ((u32)us[5] << 16);
  p0.w = (u32)us[6] | ((u32)us[7] << 16);
  p1.x = (u32)us[8] | ((u32)us[9] << 16);
  p1.y = (u32)us[10] | ((u32)us[11] << 16);
  p1.z = (u32)us[12] | ((u32)us[13] << 16);
  p1.w = (u32)us[14] | ((u32)us[15] << 16);
  reinterpret_cast<uint4*>(dst)[0] = p0;
  reinterpret_cast<uint4*>(dst)[1] = p1;
}

// ---------- fused: M_o = xb @ Tb_o^T (MFMA -> LDS), then pairwise L1+exp+sum ----------
// Grid (64 o, 4 i-chunks of 64) = 256 blocks, 512 thr. LDS 88.3 KB -> 1 block/CU.
#define MROW 276   // fp32 row stride: 16B-aligned, 2-way-free MFMA D-stores
__global__ __launch_bounds__(512, 2) void md_fused(const u16* __restrict__ Tb,
                                                   const u16* __restrict__ xb,
                                                   float* __restrict__ out) {
  const int o = blockIdx.x;            // 0..63
  const int ibase = blockIdx.y << 6;   // 64 i per block
  const int tid = threadIdx.x;

  __shared__ float Ms[80 * MROW];      // M_o[k][b], 88,320 B

  // ---- phase 1: Ms[k][b] = sum_f Tb[o][k][f] * xb[b][f], wave w owns b in [32w,32w+32)
  {
    const int l = tid & 63, w = tid >> 6;
    const int b0 = w << 5;
    const int lr = l & 15;
    const int ko = (l >> 4) << 3;      // 8 contiguous k-elems per lane group
    const u16* A = Tb + o * (80 * 512);
    const u16* B0 = xb + (b0 + lr) * 512 + ko;
    const u16* B1 = B0 + 16 * 512;
#pragma unroll
    for (int kt = 0; kt < 5; ++kt) {
      const u16* Ak = A + (kt * 16 + lr) * 512 + ko;
      f32x4 d0 = {0.f, 0.f, 0.f, 0.f}, d1 = d0;
#pragma unroll 4
      for (int ks = 0; ks < 16; ++ks) {
        const bf16x8 a  = *reinterpret_cast<const bf16x8*>(Ak + (ks << 5));
        const bf16x8 f0 = *reinterpret_cast<const bf16x8*>(B0 + (ks << 5));
        const bf16x8 f1 = *reinterpret_cast<const bf16x8*>(B1 + (ks << 5));
        d0 = __builtin_amdgcn_mfma_f32_16x16x32_bf16(a, f0, d0, 0, 0, 0);
        d1 = __builtin_amdgcn_mfma_f32_16x16x32_bf16(a, f1, d1, 0, 0, 0);
      }
      // D: col(=b)=lane&15, row(=k)= (lane>>4)*4 + r   [m89-verified]
#pragma unroll
      for (int r = 0; r < 4; ++r) {
        const int k = kt * 16 + ((l >> 4) << 2) + r;
        Ms[k * MROW + b0 + lr] = d0[r];
        Ms[k * MROW + b0 + 16 + lr] = d1[r];
      }
    }
  }
  __syncthreads();

  // ---- phase 2: pairwise. Thread (io,jg): 2 i x 16 j. Rows k=0..74 only.
  const int io = tid & 31;             // i-slot: i_local = 2*io (+e)
  const int jg = tid >> 5;             // 0..15 -> j in [16*jg, 16*jg+16)
  const int iL = ibase + (io << 1);    // global column index of own rows

  float d0a[16], d1a[16];
#pragma unroll
  for (int q = 0; q < 16; ++q) { d0a[q] = 0.0f; d1a[q] = 0.0f; }

  for (int k = 0; k < 75; ++k) {
    const float* row = Ms + k * MROW;
    const float mi0 = row[iL];
    const float mi1 = row[iL + 1];
    const float4* row4 = reinterpret_cast<const float4*>(row) + (jg << 2);
#pragma unroll
    for (int q = 0; q < 4; ++q) {
      const float4 v = row4[q];        // 2 distinct addrs/wave -> broadcast
      d0a[4 * q + 0] += __builtin_fabsf(v.x - mi0);
      d0a[4 * q + 1] += __builtin_fabsf(v.y - mi0);
      d0a[4 * q + 2] += __builtin_fabsf(v.z - mi0);
      d0a[4 * q + 3] += __builtin_fabsf(v.w - mi0);
      d1a[4 * q + 0] += __builtin_fabsf(v.x - mi1);
      d1a[4 * q + 1] += __builtin_fabsf(v.y - mi1);
      d1a[4 * q + 2] += __builtin_fabsf(v.z - mi1);
      d1a[4 * q + 3] += __builtin_fabsf(v.w - mi1);
    }
  }

  float s0 = 0.0f, s1 = 0.0f;
#pragma unroll
  for (int q = 0; q < 16; ++q) {
    s0 += __expf(-d0a[q]);             // j==i term exp(0)=1 cancels the -1
    s1 += __expf(-d1a[q]);
  }

  __syncthreads();                     // Ms reads done before overlay
  float* red = Ms;                     // red[i_local][jg], stride 17: conflict-free
  red[((io << 1) + 0) * 17 + jg] = s0;
  red[((io << 1) + 1) * 17 + jg] = s1;
  __syncthreads();
  if (tid < 64) {
    float s = 0.0f;
#pragma unroll
    for (int g = 0; g < 16; ++g) s += red[tid * 17 + g];
    out[(ibase + tid) * 64 + o] = s - 1.0f;
  }
}

extern "C" void kernel_launch(void* const* d_in, const int* in_sizes, int n_in,
                              void* d_out, int out_size, void* d_ws, size_t ws_size,
                              hipStream_t stream) {
  const float* x = (const float*)d_in[0];   // [256,512]
  const float* T = (const float*)d_in[1];   // [512,75,64]
  float* out = (float*)d_out;               // [256,64]

  char* ws = (char*)d_ws;
  u16* Tb = (u16*)ws;                       // 5,242,880 B
  u16* xb = (u16*)(ws + 5242880);           //   262,144 B

  cvt_x<<<64, 256, 0, stream>>>(x, xb);
  cvt_T<<<dim3(8, 80), 256, 0, stream>>>(T, Tb);
  md_fused<<<dim3(64, 4), 512, 0, stream>>>(Tb, xb, out);
}

// Round 7
// 53.239 us; speedup vs baseline: 1.6407x; 1.6407x over previous
//
#include <hip/hip_runtime.h>

// B=256, IN_F=512, K_INT=75, OUT_F=64
// ws: Mt[o][k][b] fp32    @ 0          (4,915,200 B)
//     Tb[k*64+o][f] bf16  @ 4,915,200  (4,915,200 B)
//     xb[b][f] bf16       @ 9,830,400  (  262,144 B)
//     ps[o][g][c][64] f32 @ 10,092,544 (  262,144 B)

typedef __attribute__((ext_vector_type(8))) short bf16x8;
typedef __attribute__((ext_vector_type(4))) float f32x4;
typedef unsigned short u16;
typedef unsigned int u32;

__device__ inline u16 f2bf(float f) {            // RNE float->bf16 bits
  u32 u = __float_as_uint(f);
  return (u16)((u + 0x7FFFu + ((u >> 16) & 1u)) >> 16);
}

// ---------- x[256][512] fp32 -> xb[b][f] bf16 (verbatim R5) ----------
__global__ __launch_bounds__(256) void cvt_x(const float* __restrict__ x,
                                             u16* __restrict__ xb) {
  const int i = blockIdx.x * 256 + threadIdx.x;
  const float4* x4 = reinterpret_cast<const float4*>(x);
  const float4 v0 = x4[i * 2], v1 = x4[i * 2 + 1];
  uint4 o;
  o.x = (u32)f2bf(v0.x) | ((u32)f2bf(v0.y) << 16);
  o.y = (u32)f2bf(v0.z) | ((u32)f2bf(v0.w) << 16);
  o.z = (u32)f2bf(v1.x) | ((u32)f2bf(v1.y) << 16);
  o.w = (u32)f2bf(v1.z) | ((u32)f2bf(v1.w) << 16);
  *reinterpret_cast<uint4*>(xb + i * 8) = o;
}

// ---------- T[f][k][o] fp32 -> Tb[k*64+o][f] bf16 (verbatim R5) ----------
__global__ __launch_bounds__(256) void cvt_T(const float* __restrict__ T,
                                             u16* __restrict__ Tb) {
  const int f0 = blockIdx.x << 6;
  const int k = blockIdx.y;          // 0..74
  const int tid = threadIdx.x;
  __shared__ float tile[64][65];

  const float4* T4 = reinterpret_cast<const float4*>(T);
  const int r = tid >> 2;
  const int c = tid & 3;
#pragma unroll
  for (int h = 0; h < 4; ++h) {
    const int q = c + (h << 2);
    const float4 v = T4[(f0 + r) * 1200 + k * 16 + q];
    tile[r][(q << 2) + 0] = v.x;
    tile[r][(q << 2) + 1] = v.y;
    tile[r][(q << 2) + 2] = v.z;
    tile[r][(q << 2) + 3] = v.w;
  }
  __syncthreads();

  const int w = tid >> 2;
  u16 us[16];
#pragma unroll
  for (int j = 0; j < 16; ++j) us[j] = f2bf(tile[(c << 4) + j][w]);
  uint4 p0, p1;
  p0.x = (u32)us[0] | ((u32)us[1] << 16);
  p0.y = (u32)us[2] | ((u32)us[3] << 16);
  p0.z = (u32)us[4] | ((u32)us[5] << 16);
  p0.w = (u32)us[6] | ((u32)us[7] << 16);
  p1.x = (u32)us[8] | ((u32)us[9] << 16);
  p1.y = (u32)us[10] | ((u32)us[11] << 16);
  p1.z = (u32)us[12] | ((u32)us[13] << 16);
  p1.w = (u32)us[14] | ((u32)us[15] << 16);
  uint4* dst = reinterpret_cast<uint4*>(Tb + ((k << 6) + w) * 512 + f0 + (c << 4));
  dst[0] = p0;
  dst[1] = p1;
}

// ---------- MFMA GEMM (verbatim R5): Mt[o][k][b] = sum_f Tb[k*64+o][f]*xb[b][f] ----------
__global__ __launch_bounds__(256) void md_gemm_mfma(const u16* __restrict__ Tb,
                                                    const u16* __restrict__ xb,
                                                    float* __restrict__ Mt) {
  const int tid = threadIdx.x;
  const int l = tid & 63, w = tid >> 6;
  const int n0 = (blockIdx.x << 6) + ((w >> 1) << 5);
  const int b0 = (blockIdx.y << 6) + ((w & 1) << 5);
  const int lr = l & 15;
  const int ko = (l >> 4) << 3;

  const u16* pa0 = Tb + (n0 + lr) * 512 + ko;
  const u16* pa1 = pa0 + 16 * 512;
  const u16* pb0 = xb + (b0 + lr) * 512 + ko;
  const u16* pb1 = pb0 + 16 * 512;

  f32x4 d00 = {0.f, 0.f, 0.f, 0.f}, d01 = d00, d10 = d00, d11 = d00;

#pragma unroll 4
  for (int kk = 0; kk < 16; ++kk) {
    const int off = kk << 5;
    const bf16x8 a0 = *reinterpret_cast<const bf16x8*>(pa0 + off);
    const bf16x8 a1 = *reinterpret_cast<const bf16x8*>(pa1 + off);
    const bf16x8 f0 = *reinterpret_cast<const bf16x8*>(pb0 + off);
    const bf16x8 f1 = *reinterpret_cast<const bf16x8*>(pb1 + off);
    d00 = __builtin_amdgcn_mfma_f32_16x16x32_bf16(a0, f0, d00, 0, 0, 0);
    d01 = __builtin_amdgcn_mfma_f32_16x16x32_bf16(a0, f1, d01, 0, 0, 0);
    d10 = __builtin_amdgcn_mfma_f32_16x16x32_bf16(a1, f0, d10, 0, 0, 0);
    d11 = __builtin_amdgcn_mfma_f32_16x16x32_bf16(a1, f1, d11, 0, 0, 0);
  }

#pragma unroll
  for (int r = 0; r < 4; ++r) {
    const int row = ((l >> 4) << 2) + r;
    {
      const int n = n0 + row;
      float* base = Mt + (n & 63) * 19200 + (n >> 6) * 256;
      base[b0 + lr] = d00[r];
      base[b0 + 16 + lr] = d01[r];
    }
    {
      const int n = n0 + 16 + row;
      float* base = Mt + (n & 63) * 19200 + (n >> 6) * 256;
      base[b0 + lr] = d10[r];
      base[b0 + 16 + lr] = d11[r];
    }
  }
}

// ---------- symmetric tiled pairwise: one 64x64 (i,j) tile per block ----------
// Grid 640 = 10 tile-pairs x 64 o (bid = tp*64+o -> same-o blocks on same XCD).
// 256 thr: lane tile 4i x 4j. LDS 38.4KB -> 4 blocks/CU -> 16 waves/CU.
__global__ __launch_bounds__(256) void md_pair_sym(const float* __restrict__ Mt,
                                                   float* __restrict__ ps) {
  const int bid = blockIdx.x;
  const int o = bid & 63;
  const int tp = bid >> 6;                 // 0..9
  const int TI[10] = {0, 0, 0, 0, 1, 1, 1, 2, 2, 3};
  const int TJ[10] = {0, 1, 2, 3, 1, 2, 3, 2, 3, 3};
  const int ti = TI[tp], tj = TJ[tp];
  const int tid = threadIdx.x;
  const bool diag = (ti == tj);

  __shared__ alignas(16) float sm[2 * 75 * 64];   // 38,400 B
  float4* Mi4 = reinterpret_cast<float4*>(sm);            // [75][16] float4
  float4* Mj4 = diag ? Mi4 : Mi4 + 75 * 16;

  // stage column panels: Mt[o][k][t*64 .. +64) -> 1200 float4 each, coalesced 256B/k-row
  {
    const float4* src = reinterpret_cast<const float4*>(Mt + o * 19200 + ti * 64);
    for (int t = tid; t < 1200; t += 256) {
      const int k = t >> 4, q = t & 15;
      Mi4[k * 16 + q] = src[k * 64 + q];
    }
    if (!diag) {
      const float4* srj = reinterpret_cast<const float4*>(Mt + o * 19200 + tj * 64);
      for (int t = tid; t < 1200; t += 256) {
        const int k = t >> 4, q = t & 15;
        Mj4[k * 16 + q] = srj[k * 64 + q];
      }
    }
  }
  __syncthreads();

  const int io = tid & 15;         // i-slot: i_local = 4*io + a
  const int js = tid >> 4;         // j-slot: j_local = 4*js + b

  float d[4][4];
#pragma unroll
  for (int a = 0; a < 4; ++a)
#pragma unroll
    for (int b = 0; b < 4; ++b) d[a][b] = 0.0f;

  for (int k = 0; k < 75; ++k) {
    const float4 vi = Mi4[k * 16 + io];   // 16 distinct b128 addrs -> <=2-way (free)
    const float4 vj = Mj4[k * 16 + js];   // 4 distinct addrs/wave -> broadcast
    const float via[4] = {vi.x, vi.y, vi.z, vi.w};
    const float vja[4] = {vj.x, vj.y, vj.z, vj.w};
#pragma unroll
    for (int a = 0; a < 4; ++a)
#pragma unroll
      for (int b = 0; b < 4; ++b) d[a][b] += __builtin_fabsf(vja[b] - via[a]);
  }

  float isum[4] = {0.f, 0.f, 0.f, 0.f};
  float jsum[4] = {0.f, 0.f, 0.f, 0.f};
#pragma unroll
  for (int a = 0; a < 4; ++a)
#pragma unroll
    for (int b = 0; b < 4; ++b) {
      const float e = __expf(-d[a][b]);   // diag: j==i gives exp(0)=1, cancelled by -1 later
      isum[a] += e;
      jsum[b] += e;
    }

  __syncthreads();                  // panel reads done; overlay reduce scratch on sm
  float* red = sm;                  // red[row][slot], stride 17
#pragma unroll
  for (int a = 0; a < 4; ++a) red[((io << 2) + a) * 17 + js] = isum[a];
  __syncthreads();
  if (tid < 64) {
    float s = 0.0f;
#pragma unroll
    for (int c = 0; c < 16; ++c) s += red[tid * 17 + c];
    ps[(((o << 2) + ti) << 2 | tj) * 64 + tid] = s;     // slot [o][ti][tj]
  }
  if (!diag) {
    __syncthreads();
#pragma unroll
    for (int b = 0; b < 4; ++b) red[((js << 2) + b) * 17 + io] = jsum[b];
    __syncthreads();
    if (tid < 64) {
      float s = 0.0f;
#pragma unroll
      for (int c = 0; c < 16; ++c) s += red[tid * 17 + c];
      ps[(((o << 2) + tj) << 2 | ti) * 64 + tid] = s;   // slot [o][tj][ti]
    }
  }
}

// ---------- final: out[i][o] = sum_c ps[o][g(i)][c][i&63] - 1 ----------
__global__ __launch_bounds__(256) void md_reduce(const float* __restrict__ ps,
                                                 float* __restrict__ out) {
  const int idx = blockIdx.x * 256 + threadIdx.x;   // 0..16383
  const int i = idx >> 6, o = idx & 63;
  const int g = i >> 6, il = i & 63;
  float s = 0.0f;
#pragma unroll
  for (int c = 0; c < 4; ++c) s += ps[(((o << 2) + g) << 2 | c) * 64 + il];
  out[i * 64 + o] = s - 1.0f;
}

extern "C" void kernel_launch(void* const* d_in, const int* in_sizes, int n_in,
                              void* d_out, int out_size, void* d_ws, size_t ws_size,
                              hipStream_t stream) {
  const float* x = (const float*)d_in[0];   // [256,512]
  const float* T = (const float*)d_in[1];   // [512,75,64]
  float* out = (float*)d_out;               // [256,64]

  char* ws = (char*)d_ws;
  float* Mt = (float*)ws;                   // 4,915,200 B
  u16* Tb = (u16*)(ws + 4915200);           // 4,915,200 B
  u16* xb = (u16*)(ws + 9830400);           //   262,144 B
  float* ps = (float*)(ws + 10092544);      //   262,144 B

  cvt_x<<<64, 256, 0, stream>>>(x, xb);
  cvt_T<<<dim3(8, 75), 256, 0, stream>>>(T, Tb);
  md_gemm_mfma<<<dim3(75, 4), 256, 0, stream>>>(Tb, xb, Mt);
  md_pair_sym<<<640, 256, 0, stream>>>(Mt, ps);
  md_reduce<<<64, 256, 0, stream>>>(ps, out);
}